// Round 1
// baseline (222.151 us; speedup 1.0000x reference)
//
#include <hip/hip_runtime.h>

// DoReFa dense: out = q_in(3-bit) @ (sign(W)*E) + b,  E = mean|W|
//   q_in = round(min(1,|x|)*7)/7  -> integer r in 0..7
//   => out[i,j] = (E/7) * sum_k r[i,k]*sign(W[k,j])  -- exact in int8 MFMA.
// inputs: d_in[0]=inputs f32[8192,4096], d_in[1]=W f32[4096,4096], d_in[2]=b f32[4096]
// output: f32[8192,4096]

static constexpr int BATCH  = 8192;
static constexpr int IN_CH  = 4096;
static constexpr int NUNITS = 4096;
static constexpr int TPB    = 256;

typedef int v4i  __attribute__((ext_vector_type(4)));

// ---- workspace layout ----
static constexpr size_t A8_OFF   = 0;
static constexpr size_t A8_BYTES = (size_t)BATCH * IN_CH;    // 33554432
static constexpr size_t BT_OFF   = A8_OFF + A8_BYTES;
static constexpr size_t BT_BYTES = (size_t)NUNITS * IN_CH;   // 16777216
static constexpr int    NPART    = 2048;
static constexpr size_t PART_OFF = BT_OFF + BT_BYTES;
static constexpr size_t SCALE_OFF= PART_OFF + NPART * sizeof(float);

// ---------------------------------------------------------------- reductions
__global__ __launch_bounds__(TPB) void k_abs_partial(const float* __restrict__ W,
                                                     float* __restrict__ partials) {
    __shared__ float red[TPB];
    const size_t tid = (size_t)blockIdx.x * TPB + threadIdx.x;   // 524288 threads
    const float4* W4 = (const float4*)W;                          // 4194304 float4
    float s = 0.f;
#pragma unroll
    for (int i = 0; i < 8; ++i) {
        float4 v = W4[tid + (size_t)i * 524288];
        s += fabsf(v.x) + fabsf(v.y) + fabsf(v.z) + fabsf(v.w);
    }
    red[threadIdx.x] = s;
    __syncthreads();
    for (int off = TPB / 2; off > 0; off >>= 1) {
        if ((int)threadIdx.x < off) red[threadIdx.x] += red[threadIdx.x + off];
        __syncthreads();
    }
    if (threadIdx.x == 0) partials[blockIdx.x] = red[0];
}

__global__ __launch_bounds__(TPB) void k_scale(const float* __restrict__ partials,
                                               float* __restrict__ scale) {
    __shared__ float red[TPB];
    float s = 0.f;
    for (int i = threadIdx.x; i < NPART; i += TPB) s += partials[i];
    red[threadIdx.x] = s;
    __syncthreads();
    for (int off = TPB / 2; off > 0; off >>= 1) {
        if ((int)threadIdx.x < off) red[threadIdx.x] += red[threadIdx.x + off];
        __syncthreads();
    }
    if (threadIdx.x == 0) {
        float E = red[0] / (float)((size_t)IN_CH * NUNITS);
        *scale = E / 7.0f;
    }
}

// ------------------------------------------------------------- quantize A
__device__ __forceinline__ unsigned int q4(float4 v) {
    unsigned int b0 = (unsigned int)(int)rintf(fminf(1.0f, fabsf(v.x)) * 7.0f);
    unsigned int b1 = (unsigned int)(int)rintf(fminf(1.0f, fabsf(v.y)) * 7.0f);
    unsigned int b2 = (unsigned int)(int)rintf(fminf(1.0f, fabsf(v.z)) * 7.0f);
    unsigned int b3 = (unsigned int)(int)rintf(fminf(1.0f, fabsf(v.w)) * 7.0f);
    return b0 | (b1 << 8) | (b2 << 16) | (b3 << 24);
}

__global__ __launch_bounds__(TPB) void k_quant_a(const float4* __restrict__ x4,
                                                 uint4* __restrict__ a16) {
    const size_t t = (size_t)blockIdx.x * TPB + threadIdx.x;  // 2097152 threads
    uint4 o;
    o.x = q4(x4[t * 4 + 0]);
    o.y = q4(x4[t * 4 + 1]);
    o.z = q4(x4[t * 4 + 2]);
    o.w = q4(x4[t * 4 + 3]);
    a16[t] = o;
}

// ------------------------------------------------- sign(W) transposed to [N][K]
__global__ __launch_bounds__(TPB) void k_signT(const float* __restrict__ W,
                                               char* __restrict__ bt) {
    __shared__ char tile[64][68];   // +4 pad: 2-way max on both phases
    const int bk = blockIdx.x & 63;      // IN_CH / 64
    const int bn = blockIdx.x >> 6;      // NUNITS / 64
    const int t  = threadIdx.x;
    const int c  = t & 63;
    const int r0 = t >> 6;
#pragma unroll
    for (int i = 0; i < 16; ++i) {
        int r = i * 4 + r0;
        float w = W[(size_t)(bk * 64 + r) * NUNITS + bn * 64 + c];
        tile[c][r] = (w > 0.f) ? 1 : ((w < 0.f) ? -1 : 0);
    }
    __syncthreads();
    const int n  = t >> 2;
    const int kk = (t & 3) * 16;
    char o[16];
#pragma unroll
    for (int j = 0; j < 16; ++j) o[j] = tile[n][kk + j];
    *(uint4*)(bt + (size_t)(bn * 64 + n) * IN_CH + bk * 64 + kk) = *(const uint4*)o;
}

// ---------------------------------------------------------------- GEMM
// C[8192,4096] = scale * (A8[8192,4096] i8 x BT[4096,4096]^T i8) + bias
// 128x128 tile, BK=64, 4 waves (2x2), mfma_i32_16x16x64_i8.
__device__ __forceinline__ void gload_lds16(const void* g, void* l) {
    __builtin_amdgcn_global_load_lds((const __attribute__((address_space(1))) void*)g,
                                     (__attribute__((address_space(3))) void*)l,
                                     16, 0, 0);
}

__global__ __launch_bounds__(TPB) void k_gemm(const char* __restrict__ A8,
                                              const char* __restrict__ BT,
                                              const float* __restrict__ scale_p,
                                              const float* __restrict__ bias,
                                              float* __restrict__ out) {
    __shared__ char As[128 * 64];
    __shared__ char Bs[128 * 64];
    const int t    = threadIdx.x;
    const int bCol = blockIdx.x & 31;   // NUNITS/128
    const int bRow = blockIdx.x >> 5;   // BATCH/128
    const int lane = t & 63;
    const int w    = t >> 6;
    const int wr   = w >> 1, wc = w & 1;

    v4i acc[4][4] = {};

    const int lrow = lane & 15;
    const int lk   = (lane >> 4) * 16;

    const size_t aBase = (size_t)(bRow * 128) * IN_CH;
    const size_t bBase = (size_t)(bCol * 128) * IN_CH;

    for (int k0 = 0; k0 < IN_CH; k0 += 64) {
        __syncthreads();
#pragma unroll
        for (int issue = 0; issue < 2; ++issue) {
            const int idx = issue * 4096 + t * 16;
            const int row = idx >> 6, off = idx & 63;
            gload_lds16(A8 + aBase + (size_t)row * IN_CH + k0 + off, As + idx);
            gload_lds16(BT + bBase + (size_t)row * IN_CH + k0 + off, Bs + idx);
        }
        __syncthreads();
        v4i a[4], b[4];
#pragma unroll
        for (int m = 0; m < 4; ++m)
            a[m] = *(const v4i*)(As + (wr * 64 + m * 16 + lrow) * 64 + lk);
#pragma unroll
        for (int n = 0; n < 4; ++n)
            b[n] = *(const v4i*)(Bs + (wc * 64 + n * 16 + lrow) * 64 + lk);
#pragma unroll
        for (int m = 0; m < 4; ++m)
#pragma unroll
            for (int n = 0; n < 4; ++n)
                acc[m][n] = __builtin_amdgcn_mfma_i32_16x16x64_i8(a[m], b[n], acc[m][n], 0, 0, 0);
    }

    const float scale = *scale_p;
    const int orow0 = bRow * 128 + wr * 64;
    const int ocol0 = bCol * 128 + wc * 64;
#pragma unroll
    for (int m = 0; m < 4; ++m) {
#pragma unroll
        for (int n = 0; n < 4; ++n) {
            const int col = ocol0 + n * 16 + (lane & 15);
            const float bb = bias[col];
            const int rbase = orow0 + m * 16 + (lane >> 4) * 4;
#pragma unroll
            for (int j = 0; j < 4; ++j) {
                out[(size_t)(rbase + j) * NUNITS + col] = scale * (float)acc[m][n][j] + bb;
            }
        }
    }
}

// ---------------------------------------------------------------- launch
extern "C" void kernel_launch(void* const* d_in, const int* in_sizes, int n_in,
                              void* d_out, int out_size, void* d_ws, size_t ws_size,
                              hipStream_t stream) {
    const float* x  = (const float*)d_in[0];
    const float* W  = (const float*)d_in[1];
    const float* b  = (const float*)d_in[2];
    float* out      = (float*)d_out;

    char*  ws       = (char*)d_ws;
    char*  A8       = ws + A8_OFF;
    char*  BT       = ws + BT_OFF;
    float* partials = (float*)(ws + PART_OFF);
    float* scale    = (float*)(ws + SCALE_OFF);

    k_abs_partial<<<NPART, TPB, 0, stream>>>(W, partials);
    k_scale<<<1, TPB, 0, stream>>>(partials, scale);
    k_quant_a<<<(BATCH * (IN_CH / 16)) / TPB, TPB, 0, stream>>>((const float4*)x, (uint4*)A8);
    k_signT<<<(IN_CH / 64) * (NUNITS / 64), TPB, 0, stream>>>(W, BT);
    k_gemm<<<(BATCH / 128) * (NUNITS / 128), TPB, 0, stream>>>(A8, BT, scale, b, out);
}

// Round 2
// 184.973 us; speedup vs baseline: 1.2010x; 1.2010x over previous
//
#include <hip/hip_runtime.h>

// DoReFa dense: out = q_in(3-bit) @ (sign(W)*E) + b,  E = mean|W|
//   out[i,j] = (E/7) * sum_k r[i,k]*sign(W[k,j]),  r in 0..7 -- exact in i8 MFMA.
// R2: 256x256 8-phase i8 GEMM (T1 XCD-swz + T2 LDS-swz + T3/T4 counted vmcnt + T5 setprio),
//     |W| reduction fused into sign-transpose kernel.

static constexpr int BATCH  = 8192;
static constexpr int IN_CH  = 4096;
static constexpr int NUNITS = 4096;
static constexpr int TPB    = 256;

typedef int v4i __attribute__((ext_vector_type(4)));

// ---- workspace layout ----
static constexpr size_t A8_OFF   = 0;
static constexpr size_t A8_BYTES = (size_t)BATCH * IN_CH;    // 32 MB
static constexpr size_t BT_OFF   = A8_OFF + A8_BYTES;
static constexpr size_t BT_BYTES = (size_t)NUNITS * IN_CH;   // 16 MB
static constexpr int    NPART    = 4096;                     // one per signT block
static constexpr size_t PART_OFF = BT_OFF + BT_BYTES;
static constexpr size_t SCALE_OFF= PART_OFF + NPART * sizeof(float);

// ------------------------------------------------------------- scale finalize
__global__ __launch_bounds__(TPB) void k_scale(const float* __restrict__ partials,
                                               float* __restrict__ scale) {
    __shared__ float red[TPB];
    float s = 0.f;
    for (int i = threadIdx.x; i < NPART; i += TPB) s += partials[i];
    red[threadIdx.x] = s;
    __syncthreads();
    for (int off = TPB / 2; off > 0; off >>= 1) {
        if ((int)threadIdx.x < off) red[threadIdx.x] += red[threadIdx.x + off];
        __syncthreads();
    }
    if (threadIdx.x == 0) {
        float E = red[0] / (float)((size_t)IN_CH * NUNITS);
        *scale = E / 7.0f;
    }
}

// ------------------------------------------------------------- quantize A
__device__ __forceinline__ unsigned int q4(float4 v) {
    unsigned int b0 = (unsigned int)(int)rintf(fminf(1.0f, fabsf(v.x)) * 7.0f);
    unsigned int b1 = (unsigned int)(int)rintf(fminf(1.0f, fabsf(v.y)) * 7.0f);
    unsigned int b2 = (unsigned int)(int)rintf(fminf(1.0f, fabsf(v.z)) * 7.0f);
    unsigned int b3 = (unsigned int)(int)rintf(fminf(1.0f, fabsf(v.w)) * 7.0f);
    return b0 | (b1 << 8) | (b2 << 16) | (b3 << 24);
}

__global__ __launch_bounds__(TPB) void k_quant_a(const float4* __restrict__ x4,
                                                 uint4* __restrict__ a16) {
    const size_t t = (size_t)blockIdx.x * TPB + threadIdx.x;
    uint4 o;
    o.x = q4(x4[t * 4 + 0]);
    o.y = q4(x4[t * 4 + 1]);
    o.z = q4(x4[t * 4 + 2]);
    o.w = q4(x4[t * 4 + 3]);
    a16[t] = o;
}

// -------------------------- sign(W) transpose to [N][K]  +  fused |W| partial sum
__global__ __launch_bounds__(TPB) void k_signT(const float* __restrict__ W,
                                               char* __restrict__ bt,
                                               float* __restrict__ partials) {
    __shared__ char tile[64][68];
    __shared__ float red[TPB];
    const int bk = blockIdx.x & 63;      // IN_CH / 64
    const int bn = blockIdx.x >> 6;      // NUNITS / 64
    const int t  = threadIdx.x;
    const int c  = t & 63;
    const int r0 = t >> 6;
    float asum = 0.f;
#pragma unroll
    for (int i = 0; i < 16; ++i) {
        int r = i * 4 + r0;
        float w = W[(size_t)(bk * 64 + r) * NUNITS + bn * 64 + c];
        asum += fabsf(w);
        tile[c][r] = (w > 0.f) ? 1 : ((w < 0.f) ? -1 : 0);
    }
    __syncthreads();
    const int n  = t >> 2;
    const int kk = (t & 3) * 16;
    char o[16];
#pragma unroll
    for (int j = 0; j < 16; ++j) o[j] = tile[n][kk + j];
    *(uint4*)(bt + (size_t)(bn * 64 + n) * IN_CH + bk * 64 + kk) = *(const uint4*)o;

    red[t] = asum;
    __syncthreads();
    for (int off = TPB / 2; off > 0; off >>= 1) {
        if (t < off) red[t] += red[t + off];
        __syncthreads();
    }
    if (t == 0) partials[blockIdx.x] = red[0];
}

// ---------------------------------------------------------------- GEMM
// C[8192,4096] = scale * (A8 i8 x BT^T i8) + bias
// 256x256 tile, BK=128 bytes, 8 waves (2Mx4N), mfma_i32_16x16x64_i8,
// 4 phases/K-tile, counted vmcnt(8), LDS XOR-swizzle, setprio around MFMA.
__device__ __forceinline__ void gload_lds16(const void* g, void* l) {
    __builtin_amdgcn_global_load_lds((const __attribute__((address_space(1))) void*)g,
                                     (__attribute__((address_space(3))) void*)l,
                                     16, 0, 0);
}

#define VMCNT8   asm volatile("s_waitcnt vmcnt(8)" ::: "memory")
#define VMCNT0   asm volatile("s_waitcnt vmcnt(0)" ::: "memory")
#define LGKM0    asm volatile("s_waitcnt lgkmcnt(0)" ::: "memory")
#define SCHEDB   __builtin_amdgcn_sched_barrier(0)
#define BARRIER  __builtin_amdgcn_s_barrier()

static constexpr int NT = IN_CH / 128;   // 32 K-tiles

__global__ __launch_bounds__(512, 2) void k_gemm(const char* __restrict__ A8,
                                                 const char* __restrict__ BT,
                                                 const float* __restrict__ scale_p,
                                                 const float* __restrict__ bias,
                                                 float* __restrict__ out) {
    __shared__ char As[2][32768];   // [256 rows][128 B], XOR-swizzled
    __shared__ char Bs[2][32768];

    const int t    = threadIdx.x;
    const int bid  = blockIdx.x;                 // 512 blocks
    const int swzb = (bid & 7) * 64 + (bid >> 3);// XCD-aware (bijective: 512%8==0)
    const int bRow = swzb >> 4;                  // 0..31
    const int bCol = swzb & 15;                  // 0..15
    const int lane = t & 63;
    const int wid  = t >> 6;
    const int wm   = wid >> 2;                   // 0..1
    const int wn   = wid & 3;                    // 0..3
    const int lr   = lane & 15;
    const int lk4  = lane >> 4;                  // 0..3

    const size_t aBase = (size_t)(bRow * 256) * IN_CH;
    const size_t bBase = (size_t)(bCol * 256) * IN_CH;

    // swizzled read column offsets: col(s) = s*64 + lk4*16, XOR ((row&7)<<4); row&7 == lr&7
    const int ceff0 = (lk4 * 16) ^ ((lr & 7) << 4);
    const int ceff1 = ceff0 ^ 64;

    // per-thread staging addressing: issue q covers rows (q&3)*64 + (t>>3), col (t&7)*16
    const int srow  = t >> 3;                    // 0..63 (q adds q*64; (r&7)==(srow&7))
    const int scol  = ((t & 7) * 16) ^ ((srow & 7) << 4);  // inverse-swizzled SOURCE col
    const int sldso = t * 16;                    // linear LDS offset within 8KB chunk

    v4i acc[8][4] = {};

#define STAGE(kt, q)                                                                 \
    do {                                                                             \
        const int _b = (kt) & 1;                                                     \
        if ((q) < 4)                                                                 \
            gload_lds16(A8 + aBase + (size_t)((q) * 64 + srow) * IN_CH + (kt) * 128 + scol, \
                        &As[_b][(q & 3) * 8192 + sldso]);                            \
        else                                                                         \
            gload_lds16(BT + bBase + (size_t)(((q) - 4) * 64 + srow) * IN_CH + (kt) * 128 + scol, \
                        &Bs[_b][((q) - 4) * 8192 + sldso]);                          \
    } while (0)

    // prologue: stage K-tiles 0 and 1 (16 issues/wave outstanding)
#pragma unroll
    for (int q = 0; q < 8; ++q) STAGE(0, q);
#pragma unroll
    for (int q = 0; q < 8; ++q) STAGE(1, q);

    for (int kt = 0; kt < NT; ++kt) {
        const int buf = kt & 1;
        const char* Ab = As[buf];
        const char* Bb = Bs[buf];

        // ---- P1: wait tile landed, read all fragments, MFMA G1
        if (kt < NT - 1) { VMCNT8; } else { VMCNT0; }
        SCHEDB;
        BARRIER;               // all waves' loads for kt landed
        v4i a0[4][2], a1[4][2], bf[4][2];
#pragma unroll
        for (int m = 0; m < 4; ++m) {
            const int ra0 = (wm * 128 + m * 16 + lr) * 128;
            const int ra1 = (wm * 128 + (m + 4) * 16 + lr) * 128;
            a0[m][0] = *(const v4i*)(Ab + ra0 + ceff0);
            a0[m][1] = *(const v4i*)(Ab + ra0 + ceff1);
            a1[m][0] = *(const v4i*)(Ab + ra1 + ceff0);
            a1[m][1] = *(const v4i*)(Ab + ra1 + ceff1);
        }
#pragma unroll
        for (int n = 0; n < 4; ++n) {
            const int rb = (wn * 64 + n * 16 + lr) * 128;
            bf[n][0] = *(const v4i*)(Bb + rb + ceff0);
            bf[n][1] = *(const v4i*)(Bb + rb + ceff1);
        }
        LGKM0;                 // all reads complete -> buf is dead after next barrier
        SCHEDB;
        BARRIER;
        __builtin_amdgcn_s_setprio(1);
#pragma unroll
        for (int m = 0; m < 4; ++m)
#pragma unroll
            for (int n = 0; n < 2; ++n)
#pragma unroll
                for (int s = 0; s < 2; ++s)
                    acc[m][n] = __builtin_amdgcn_mfma_i32_16x16x64_i8(a0[m][s], bf[n][s], acc[m][n], 0, 0, 0);
        __builtin_amdgcn_s_setprio(0);
        SCHEDB;

        // ---- P2: stage 3, MFMA G2
        if (kt + 2 < NT) { STAGE(kt + 2, 0); STAGE(kt + 2, 1); STAGE(kt + 2, 2); }
        SCHEDB;
        BARRIER;
        __builtin_amdgcn_s_setprio(1);
#pragma unroll
        for (int m = 0; m < 4; ++m)
#pragma unroll
            for (int n = 2; n < 4; ++n)
#pragma unroll
                for (int s = 0; s < 2; ++s)
                    acc[m][n] = __builtin_amdgcn_mfma_i32_16x16x64_i8(a0[m][s], bf[n][s], acc[m][n], 0, 0, 0);
        __builtin_amdgcn_s_setprio(0);
        SCHEDB;

        // ---- P3: stage 3, MFMA G3
        if (kt + 2 < NT) { STAGE(kt + 2, 3); STAGE(kt + 2, 4); STAGE(kt + 2, 5); }
        SCHEDB;
        BARRIER;
        __builtin_amdgcn_s_setprio(1);
#pragma unroll
        for (int m = 0; m < 4; ++m)
#pragma unroll
            for (int n = 0; n < 2; ++n)
#pragma unroll
                for (int s = 0; s < 2; ++s)
                    acc[m + 4][n] = __builtin_amdgcn_mfma_i32_16x16x64_i8(a1[m][s], bf[n][s], acc[m + 4][n], 0, 0, 0);
        __builtin_amdgcn_s_setprio(0);
        SCHEDB;

        // ---- P4: stage 2, MFMA G4
        if (kt + 2 < NT) { STAGE(kt + 2, 6); STAGE(kt + 2, 7); }
        SCHEDB;
        BARRIER;
        __builtin_amdgcn_s_setprio(1);
#pragma unroll
        for (int m = 0; m < 4; ++m)
#pragma unroll
            for (int n = 2; n < 4; ++n)
#pragma unroll
                for (int s = 0; s < 2; ++s)
                    acc[m + 4][n] = __builtin_amdgcn_mfma_i32_16x16x64_i8(a1[m][s], bf[n][s], acc[m + 4][n], 0, 0, 0);
        __builtin_amdgcn_s_setprio(0);
        SCHEDB;
    }

    // ---- epilogue
    const float scale = *scale_p;
    const int orow0 = bRow * 256 + wm * 128;
    const int ocol0 = bCol * 256 + wn * 64;
#pragma unroll
    for (int m = 0; m < 8; ++m) {
#pragma unroll
        for (int n = 0; n < 4; ++n) {
            const int col = ocol0 + n * 16 + lr;
            const float bb = bias[col];
            const int rbase = orow0 + m * 16 + lk4 * 4;
#pragma unroll
            for (int j = 0; j < 4; ++j)
                out[(size_t)(rbase + j) * NUNITS + col] = scale * (float)acc[m][n][j] + bb;
        }
    }
#undef STAGE
}

// ---------------------------------------------------------------- launch
extern "C" void kernel_launch(void* const* d_in, const int* in_sizes, int n_in,
                              void* d_out, int out_size, void* d_ws, size_t ws_size,
                              hipStream_t stream) {
    const float* x  = (const float*)d_in[0];
    const float* W  = (const float*)d_in[1];
    const float* b  = (const float*)d_in[2];
    float* out      = (float*)d_out;

    char*  ws       = (char*)d_ws;
    char*  A8       = ws + A8_OFF;
    char*  BT       = ws + BT_OFF;
    float* partials = (float*)(ws + PART_OFF);
    float* scale    = (float*)(ws + SCALE_OFF);

    k_signT<<<(IN_CH / 64) * (NUNITS / 64), TPB, 0, stream>>>(W, BT, partials);
    k_scale<<<1, TPB, 0, stream>>>(partials, scale);
    k_quant_a<<<(BATCH * (IN_CH / 16)) / TPB, TPB, 0, stream>>>((const float4*)x, (uint4*)A8);
    k_gemm<<<(BATCH / 256) * (NUNITS / 256), 512, 0, stream>>>(A8, BT, scale, b, out);
}